// Round 1
// baseline (1225.366 us; speedup 1.0000x reference)
//
#include <hip/hip_runtime.h>

// SelfAttention: out = softmax((xWq+bq)(xWk+bk)^T) @ Wout + bout
// B=8, N=2048, D=1024. fp32 in/out.
// Strategy: bf16 MFMA with hi/lo split (3-MFMA) for the score chain
// (softmax logits have std~32, nearly one-hot -> needs ~fp32-accurate scores),
// plain bf16 MFMA for P@Wout.
//
// Pipeline: prep (transpose+split W, split x) -> GEMM Q,K -> GEMM S -> softmax -> GEMM out.
// ws layout (full mode, 268 MiB): W planes 12M | Qhi/Qlo/Khi/Klo 128M | S 128M.
//   x hi/lo planes alias the S region (dead before S is written);
//   P (bf16) aliases the Q planes (dead after S GEMM).
// Fallback per-batch loop if ws < 268 MiB (needs 44 MiB).

typedef unsigned short u16;
typedef __bf16 bf16x8 __attribute__((ext_vector_type(8)));
typedef float f32x4 __attribute__((ext_vector_type(4)));

#define BB 8
#define NN 2048
#define DD 1024
#define MT (BB * NN)

__device__ __forceinline__ u16 f2bf(float f) {
  unsigned u = __builtin_bit_cast(unsigned, f);
  u += 0x7FFFu + ((u >> 16) & 1u);
  return (u16)(u >> 16);
}
__device__ __forceinline__ float bf2f(u16 h) {
  unsigned u = ((unsigned)h) << 16;
  return __builtin_bit_cast(float, u);
}

// ---- prep: split fp32 -> hi/lo bf16 planes -------------------------------
__global__ void k_split(const float* __restrict__ x, u16* __restrict__ hi,
                        u16* __restrict__ lo, long n4) {
  long i = (long)blockIdx.x * blockDim.x + threadIdx.x;
  long stride = (long)gridDim.x * blockDim.x;
  for (; i < n4; i += stride) {
    float4 v = ((const float4*)x)[i];
    u16 h0 = f2bf(v.x), h1 = f2bf(v.y), h2 = f2bf(v.z), h3 = f2bf(v.w);
    ushort4 hv; hv.x = h0; hv.y = h1; hv.z = h2; hv.w = h3;
    ushort4 lv;
    lv.x = f2bf(v.x - bf2f(h0)); lv.y = f2bf(v.y - bf2f(h1));
    lv.z = f2bf(v.z - bf2f(h2)); lv.w = f2bf(v.w - bf2f(h3));
    ((ushort4*)hi)[i] = hv;
    ((ushort4*)lo)[i] = lv;
  }
}

// ---- prep: transpose RxC fp32 -> CxR bf16 planes (hi, optional lo) -------
__global__ void k_transpose_split(const float* __restrict__ W, u16* __restrict__ thi,
                                  u16* __restrict__ tlo, int R, int C) {
  __shared__ float tile[32][33];
  int c0 = blockIdx.x * 32, r0 = blockIdx.y * 32;
  int tx = threadIdx.x, ty = threadIdx.y;  // block (32,8)
#pragma unroll
  for (int i = 0; i < 4; i++)
    tile[ty + i * 8][tx] = W[(size_t)(r0 + ty + i * 8) * C + c0 + tx];
  __syncthreads();
#pragma unroll
  for (int i = 0; i < 4; i++) {
    float v = tile[tx][ty + i * 8];  // = W[r0+tx][c0+ty+i*8]
    size_t o = (size_t)(c0 + ty + i * 8) * R + r0 + tx;
    u16 h = f2bf(v);
    thi[o] = h;
    if (tlo) tlo[o] = f2bf(v - bf2f(h));
  }
}

// ---- GEMM1: Q,K = x @ {Wq,Wk} + bias, split output -----------------------
// A = x planes [rows][1024] hi/lo; B = WT planes [n][k] hi/lo.
// grid (mtiles, 16): nt<8 -> Q cols, nt>=8 -> K cols.
__launch_bounds__(256)
__global__ void k_gemm_qk(const u16* __restrict__ xhi, const u16* __restrict__ xlo,
                          const u16* __restrict__ wqThi, const u16* __restrict__ wqTlo,
                          const u16* __restrict__ wkThi, const u16* __restrict__ wkTlo,
                          const float* __restrict__ bq, const float* __restrict__ bk,
                          u16* __restrict__ qhi, u16* __restrict__ qlo,
                          u16* __restrict__ khi, u16* __restrict__ klo) {
  __shared__ __attribute__((aligned(16))) u16 lds[4][128][40];
  int mt = blockIdx.x, nt = blockIdx.y;
  bool isK = (nt >= 8);
  const u16* bThi = isK ? wkThi : wqThi;
  const u16* bTlo = isK ? wkTlo : wqTlo;
  const float* bias = isK ? bk : bq;
  u16* ohi = isK ? khi : qhi;
  u16* olo = isK ? klo : qlo;
  int n0 = (nt & 7) * 128;
  int m0 = mt * 128;

  int t = threadIdx.x, lane = t & 63, w = t >> 6;
  int wr = w >> 1, wc = w & 1, r16 = lane & 15, g = lane >> 4;
  int rS = t >> 1, hS = (t & 1) * 16;

  const size_t aoff = (size_t)(m0 + rS) * DD + hS;
  const size_t boff = (size_t)(n0 + rS) * DD + hS;

  f32x4 acc[4][4] = {};

  for (int k0 = 0; k0 < DD; k0 += 32) {
    *(uint4*)&lds[0][rS][hS]     = *(const uint4*)&xhi[aoff + k0];
    *(uint4*)&lds[0][rS][hS + 8] = *(const uint4*)&xhi[aoff + k0 + 8];
    *(uint4*)&lds[1][rS][hS]     = *(const uint4*)&xlo[aoff + k0];
    *(uint4*)&lds[1][rS][hS + 8] = *(const uint4*)&xlo[aoff + k0 + 8];
    *(uint4*)&lds[2][rS][hS]     = *(const uint4*)&bThi[boff + k0];
    *(uint4*)&lds[2][rS][hS + 8] = *(const uint4*)&bThi[boff + k0 + 8];
    *(uint4*)&lds[3][rS][hS]     = *(const uint4*)&bTlo[boff + k0];
    *(uint4*)&lds[3][rS][hS + 8] = *(const uint4*)&bTlo[boff + k0 + 8];
    __syncthreads();
    bf16x8 bh[4], bl[4];
#pragma unroll
    for (int fn = 0; fn < 4; fn++) {
      int col = wc * 64 + fn * 16 + r16;
      bh[fn] = *(const bf16x8*)&lds[2][col][g * 8];
      bl[fn] = *(const bf16x8*)&lds[3][col][g * 8];
    }
#pragma unroll
    for (int fm = 0; fm < 4; fm++) {
      int row = wr * 64 + fm * 16 + r16;
      bf16x8 ah = *(const bf16x8*)&lds[0][row][g * 8];
      bf16x8 al = *(const bf16x8*)&lds[1][row][g * 8];
#pragma unroll
      for (int fn = 0; fn < 4; fn++) {
        acc[fm][fn] = __builtin_amdgcn_mfma_f32_16x16x32_bf16(ah, bh[fn], acc[fm][fn], 0, 0, 0);
        acc[fm][fn] = __builtin_amdgcn_mfma_f32_16x16x32_bf16(ah, bl[fn], acc[fm][fn], 0, 0, 0);
        acc[fm][fn] = __builtin_amdgcn_mfma_f32_16x16x32_bf16(al, bh[fn], acc[fm][fn], 0, 0, 0);
      }
    }
    __syncthreads();
  }
#pragma unroll
  for (int fm = 0; fm < 4; fm++) {
#pragma unroll
    for (int fn = 0; fn < 4; fn++) {
      int col = n0 + wc * 64 + fn * 16 + r16;
      float bv = bias[col];
      int row = m0 + wr * 64 + fm * 16 + g * 4;
#pragma unroll
      for (int i = 0; i < 4; i++) {
        float v = acc[fm][fn][i] + bv;
        u16 h = f2bf(v);
        size_t o = (size_t)(row + i) * DD + col;
        ohi[o] = h;
        olo[o] = f2bf(v - bf2f(h));
      }
    }
  }
}

// ---- GEMM2: S[b] = Q[b] @ K[b]^T (fp32 out), split inputs ----------------
// grid (mtS, ntS, nb): mtS = S col tile (K rows), ntS = S row tile (Q rows).
__launch_bounds__(256)
__global__ void k_gemm_s(const u16* __restrict__ qhi, const u16* __restrict__ qlo,
                         const u16* __restrict__ khi, const u16* __restrict__ klo,
                         float* __restrict__ S, size_t qb_stride, size_t sb_stride) {
  __shared__ __attribute__((aligned(16))) u16 lds[4][128][40];
  int mtS = blockIdx.x, ntS = blockIdx.y, b = blockIdx.z;
  const u16* qh = qhi + (size_t)b * qb_stride;
  const u16* ql = qlo + (size_t)b * qb_stride;
  const u16* kh = khi + (size_t)b * qb_stride;
  const u16* kl = klo + (size_t)b * qb_stride;
  float* Sb = S + (size_t)b * sb_stride;

  int t = threadIdx.x, lane = t & 63, w = t >> 6;
  int wr = w >> 1, wc = w & 1, r16 = lane & 15, g = lane >> 4;
  int rS = t >> 1, hS = (t & 1) * 16;

  const size_t aoff = (size_t)(ntS * 128 + rS) * DD + hS;
  const size_t boff = (size_t)(mtS * 128 + rS) * DD + hS;

  f32x4 acc[4][4] = {};

  for (int k0 = 0; k0 < DD; k0 += 32) {
    *(uint4*)&lds[0][rS][hS]     = *(const uint4*)&qh[aoff + k0];
    *(uint4*)&lds[0][rS][hS + 8] = *(const uint4*)&qh[aoff + k0 + 8];
    *(uint4*)&lds[1][rS][hS]     = *(const uint4*)&ql[aoff + k0];
    *(uint4*)&lds[1][rS][hS + 8] = *(const uint4*)&ql[aoff + k0 + 8];
    *(uint4*)&lds[2][rS][hS]     = *(const uint4*)&kh[boff + k0];
    *(uint4*)&lds[2][rS][hS + 8] = *(const uint4*)&kh[boff + k0 + 8];
    *(uint4*)&lds[3][rS][hS]     = *(const uint4*)&kl[boff + k0];
    *(uint4*)&lds[3][rS][hS + 8] = *(const uint4*)&kl[boff + k0 + 8];
    __syncthreads();
    bf16x8 bh[4], bl[4];
#pragma unroll
    for (int fn = 0; fn < 4; fn++) {
      int col = wc * 64 + fn * 16 + r16;
      bh[fn] = *(const bf16x8*)&lds[2][col][g * 8];
      bl[fn] = *(const bf16x8*)&lds[3][col][g * 8];
    }
#pragma unroll
    for (int fm = 0; fm < 4; fm++) {
      int row = wr * 64 + fm * 16 + r16;
      bf16x8 ah = *(const bf16x8*)&lds[0][row][g * 8];
      bf16x8 al = *(const bf16x8*)&lds[1][row][g * 8];
#pragma unroll
      for (int fn = 0; fn < 4; fn++) {
        acc[fm][fn] = __builtin_amdgcn_mfma_f32_16x16x32_bf16(ah, bh[fn], acc[fm][fn], 0, 0, 0);
        acc[fm][fn] = __builtin_amdgcn_mfma_f32_16x16x32_bf16(ah, bl[fn], acc[fm][fn], 0, 0, 0);
        acc[fm][fn] = __builtin_amdgcn_mfma_f32_16x16x32_bf16(al, bh[fn], acc[fm][fn], 0, 0, 0);
      }
    }
    __syncthreads();
  }
#pragma unroll
  for (int fm = 0; fm < 4; fm++) {
#pragma unroll
    for (int fn = 0; fn < 4; fn++) {
      int col = mtS * 128 + wc * 64 + fn * 16 + r16;
      int row = ntS * 128 + wr * 64 + fm * 16 + g * 4;
#pragma unroll
      for (int i = 0; i < 4; i++)
        Sb[(size_t)(row + i) * NN + col] = acc[fm][fn][i];
    }
  }
}

// ---- softmax rows of S -> P (bf16) ---------------------------------------
__global__ void k_softmax(const float* __restrict__ S, u16* __restrict__ P, int nrows) {
  int w = threadIdx.x >> 6, lane = threadIdx.x & 63;
  int row = blockIdx.x * 4 + w;
  if (row >= nrows) return;
  const float4* Sr = (const float4*)(S + (size_t)row * NN);
  float4 v[8];
  float mx = -3.4e38f;
#pragma unroll
  for (int j = 0; j < 8; j++) {
    v[j] = Sr[j * 64 + lane];
    mx = fmaxf(mx, fmaxf(fmaxf(v[j].x, v[j].y), fmaxf(v[j].z, v[j].w)));
  }
#pragma unroll
  for (int o = 32; o > 0; o >>= 1) mx = fmaxf(mx, __shfl_xor(mx, o));
  float e[32];
  float sum = 0.f;
#pragma unroll
  for (int j = 0; j < 8; j++) {
    e[j * 4 + 0] = __expf(v[j].x - mx);
    e[j * 4 + 1] = __expf(v[j].y - mx);
    e[j * 4 + 2] = __expf(v[j].z - mx);
    e[j * 4 + 3] = __expf(v[j].w - mx);
    sum += e[j * 4 + 0] + e[j * 4 + 1] + e[j * 4 + 2] + e[j * 4 + 3];
  }
#pragma unroll
  for (int o = 32; o > 0; o >>= 1) sum += __shfl_xor(sum, o);
  float inv = 1.0f / sum;
  ushort4* Pr = (ushort4*)(P + (size_t)row * NN);
#pragma unroll
  for (int j = 0; j < 8; j++) {
    ushort4 pv;
    pv.x = f2bf(e[j * 4 + 0] * inv);
    pv.y = f2bf(e[j * 4 + 1] * inv);
    pv.z = f2bf(e[j * 4 + 2] * inv);
    pv.w = f2bf(e[j * 4 + 3] * inv);
    Pr[j * 64 + lane] = pv;
  }
}

// ---- GEMM3: out[b] = P[b] @ Wout + bout (plain bf16) ---------------------
// grid (dt, ntt, nb). A = P rows [n][m], B = WoutT [d][m].
__launch_bounds__(256)
__global__ void k_gemm_out(const u16* __restrict__ P, const u16* __restrict__ woutT,
                           const float* __restrict__ bout, float* __restrict__ out,
                           size_t pb_stride, size_t ob_stride) {
  __shared__ __attribute__((aligned(16))) u16 lds[2][128][40];
  int dt = blockIdx.x, ntt = blockIdx.y, b = blockIdx.z;
  const u16* Pb = P + (size_t)b * pb_stride;
  float* ob = out + (size_t)b * ob_stride;

  int t = threadIdx.x, lane = t & 63, w = t >> 6;
  int wr = w >> 1, wc = w & 1, r16 = lane & 15, g = lane >> 4;
  int rS = t >> 1, hS = (t & 1) * 16;

  const size_t aoff = (size_t)(ntt * 128 + rS) * NN + hS;
  const size_t boff = (size_t)(dt * 128 + rS) * NN + hS;

  f32x4 acc[4][4] = {};

  for (int k0 = 0; k0 < NN; k0 += 32) {
    *(uint4*)&lds[0][rS][hS]     = *(const uint4*)&Pb[aoff + k0];
    *(uint4*)&lds[0][rS][hS + 8] = *(const uint4*)&Pb[aoff + k0 + 8];
    *(uint4*)&lds[1][rS][hS]     = *(const uint4*)&woutT[boff + k0];
    *(uint4*)&lds[1][rS][hS + 8] = *(const uint4*)&woutT[boff + k0 + 8];
    __syncthreads();
    bf16x8 bh[4];
#pragma unroll
    for (int fn = 0; fn < 4; fn++)
      bh[fn] = *(const bf16x8*)&lds[1][wc * 64 + fn * 16 + r16][g * 8];
#pragma unroll
    for (int fm = 0; fm < 4; fm++) {
      bf16x8 ah = *(const bf16x8*)&lds[0][wr * 64 + fm * 16 + r16][g * 8];
#pragma unroll
      for (int fn = 0; fn < 4; fn++)
        acc[fm][fn] = __builtin_amdgcn_mfma_f32_16x16x32_bf16(ah, bh[fn], acc[fm][fn], 0, 0, 0);
    }
    __syncthreads();
  }
#pragma unroll
  for (int fm = 0; fm < 4; fm++) {
#pragma unroll
    for (int fn = 0; fn < 4; fn++) {
      int col = dt * 128 + wc * 64 + fn * 16 + r16;  // d in [0,1024)
      float bv = bout[col];
      int row = ntt * 128 + wr * 64 + fm * 16 + g * 4;
#pragma unroll
      for (int i = 0; i < 4; i++)
        ob[(size_t)(row + i) * DD + col] = acc[fm][fn][i] + bv;
    }
  }
}

extern "C" void kernel_launch(void* const* d_in, const int* in_sizes, int n_in,
                              void* d_out, int out_size, void* d_ws, size_t ws_size,
                              hipStream_t stream) {
  const float* x = (const float*)d_in[0];
  const float* Wq = (const float*)d_in[1];
  const float* bq = (const float*)d_in[2];
  const float* Wk = (const float*)d_in[3];
  const float* bk = (const float*)d_in[4];
  const float* Wout = (const float*)d_in[5];
  const float* bout = (const float*)d_in[6];
  float* out = (float*)d_out;
  char* ws = (char*)d_ws;

  const size_t MB = 1ull << 20;
  u16* wqThi = (u16*)(ws + 0 * MB);
  u16* wqTlo = (u16*)(ws + 2 * MB);
  u16* wkThi = (u16*)(ws + 4 * MB);
  u16* wkTlo = (u16*)(ws + 6 * MB);
  u16* woutT = (u16*)(ws + 8 * MB);  // 4 MiB, [1024][2048]
  char* base = ws + 12 * MB;

  dim3 tb(32, 8, 1);
  k_transpose_split<<<dim3(32, 32, 1), tb, 0, stream>>>(Wq, wqThi, wqTlo, 1024, 1024);
  k_transpose_split<<<dim3(32, 32, 1), tb, 0, stream>>>(Wk, wkThi, wkTlo, 1024, 1024);
  k_transpose_split<<<dim3(32, 64, 1), tb, 0, stream>>>(Wout, woutT, (u16*)nullptr, 2048, 1024);

  bool full = ws_size >= 268ull * MB;
  if (full) {
    u16* qhi = (u16*)(base);
    u16* qlo = (u16*)(base + 32 * MB);
    u16* khi = (u16*)(base + 64 * MB);
    u16* klo = (u16*)(base + 96 * MB);
    float* S = (float*)(base + 128 * MB);  // 128 MiB
    u16* xhi = (u16*)(base + 128 * MB);    // aliases S (x dead before S written)
    u16* xlo = (u16*)(base + 160 * MB);
    u16* P = qhi;                          // aliases Q planes (64 MiB)

    k_split<<<2048, 256, 0, stream>>>(x, xhi, xlo, (long)MT * DD / 4);
    k_gemm_qk<<<dim3(128, 16, 1), 256, 0, stream>>>(xhi, xlo, wqThi, wqTlo, wkThi, wkTlo,
                                                    bq, bk, qhi, qlo, khi, klo);
    k_gemm_s<<<dim3(16, 16, 8), 256, 0, stream>>>(qhi, qlo, khi, klo, S,
                                                  (size_t)NN * DD, (size_t)NN * NN);
    k_softmax<<<MT / 4, 256, 0, stream>>>(S, P, MT);
    k_gemm_out<<<dim3(8, 16, 8), 256, 0, stream>>>(P, woutT, bout, out,
                                                   (size_t)NN * NN, (size_t)NN * DD);
  } else {
    // per-batch fallback (needs 44 MiB of ws)
    u16* qhi = (u16*)(base);
    u16* qlo = (u16*)(base + 4 * MB);
    u16* khi = (u16*)(base + 8 * MB);
    u16* klo = (u16*)(base + 12 * MB);
    float* S = (float*)(base + 16 * MB);  // 16 MiB
    u16* xhi = (u16*)(base + 16 * MB);    // aliases S
    u16* xlo = (u16*)(base + 20 * MB);
    u16* P = qhi;  // aliases Q planes (8 MiB)
    for (int b = 0; b < BB; b++) {
      const float* xb = x + (size_t)b * NN * DD;
      float* ob = out + (size_t)b * NN * DD;
      k_split<<<512, 256, 0, stream>>>(xb, xhi, xlo, (long)NN * DD / 4);
      k_gemm_qk<<<dim3(16, 16, 1), 256, 0, stream>>>(xhi, xlo, wqThi, wqTlo, wkThi, wkTlo,
                                                     bq, bk, qhi, qlo, khi, klo);
      k_gemm_s<<<dim3(16, 16, 1), 256, 0, stream>>>(qhi, qlo, khi, klo, S, 0, 0);
      k_softmax<<<NN / 4, 256, 0, stream>>>(S, P, NN);
      k_gemm_out<<<dim3(8, 16, 1), 256, 0, stream>>>(P, woutT, bout, ob, 0, 0);
    }
  }
}

// Round 2
// 604.807 us; speedup vs baseline: 2.0260x; 2.0260x over previous
//
#include <hip/hip_runtime.h>

// SelfAttention: out = softmax((xWq+bq)(xWk+bk)^T) @ Wout + bout
// B=8, N=2048, D=1024, fp32 in/out.
// bf16 MFMA with hi/lo split (3-MFMA) for the score chain, plain bf16 for P@Wout.
// Round 2: global_load_lds staging (m97 structure), batched dispatches with
// tiered ws layouts (204 / 156 / 44 MiB), XCD swizzle, in-place P over S.

typedef unsigned short u16;
typedef __bf16 bf16x8 __attribute__((ext_vector_type(8)));
typedef float f32x4 __attribute__((ext_vector_type(4)));

#define BB 8
#define NN 2048
#define DD 1024
#define MT (BB * NN)
#define PSTRIDE 4096  // u16 elems per P row (in-place over fp32 S rows)

static __device__ __forceinline__ u16 f2bf(float f) {
  unsigned u = __builtin_bit_cast(unsigned, f);
  u += 0x7FFFu + ((u >> 16) & 1u);
  return (u16)(u >> 16);
}
static __device__ __forceinline__ float bf2f(u16 h) {
  unsigned u = ((unsigned)h) << 16;
  return __builtin_bit_cast(float, u);
}

static __device__ __forceinline__ void gload16(const void* g, void* l) {
  __builtin_amdgcn_global_load_lds((const __attribute__((address_space(1))) void*)g,
                                   (__attribute__((address_space(3))) void*)l, 16, 0, 0);
}

// stage a [128][32]-u16 linear tile from gsrc (tile origin), row stride ldg elems
static __device__ __forceinline__ void stage_tile(const u16* __restrict__ gsrc,
                                                  u16* plane, int t, int ldg) {
  int w = t >> 6;
#pragma unroll
  for (int j = 0; j < 2; j++) {
    int idx = t + j * 256;  // 8-elem chunk index 0..511
    const u16* g = gsrc + (size_t)(idx >> 2) * ldg + (idx & 3) * 8;
    u16* lp = plane + (w * 64 + j * 256) * 8;  // wave-uniform base; HW adds lane*16B
    gload16(g, lp);
  }
}

// bijective XCD swizzle over a 1-D grid (gridDim.x % 8 == 0 for all callers)
static __device__ __forceinline__ int swz_wg() {
  int nwg = gridDim.x;
  int orig = blockIdx.x;
  int q = nwg >> 3;
  return (orig & 7) * q + (orig >> 3);
}

// ---- prep: split fp32 -> hi/lo bf16 planes -------------------------------
__global__ void k_split(const float* __restrict__ x, u16* __restrict__ hi,
                        u16* __restrict__ lo, long n4) {
  long i = (long)blockIdx.x * blockDim.x + threadIdx.x;
  long stride = (long)gridDim.x * blockDim.x;
  for (; i < n4; i += stride) {
    float4 v = ((const float4*)x)[i];
    u16 h0 = f2bf(v.x), h1 = f2bf(v.y), h2 = f2bf(v.z), h3 = f2bf(v.w);
    ushort4 hv; hv.x = h0; hv.y = h1; hv.z = h2; hv.w = h3;
    ushort4 lv;
    lv.x = f2bf(v.x - bf2f(h0)); lv.y = f2bf(v.y - bf2f(h1));
    lv.z = f2bf(v.z - bf2f(h2)); lv.w = f2bf(v.w - bf2f(h3));
    ((ushort4*)hi)[i] = hv;
    ((ushort4*)lo)[i] = lv;
  }
}

// ---- prep: transpose RxC fp32 -> CxR bf16 planes (hi, optional lo) -------
__global__ void k_transpose_split(const float* __restrict__ W, u16* __restrict__ thi,
                                  u16* __restrict__ tlo, int R, int C) {
  __shared__ float tile[32][33];
  int c0 = blockIdx.x * 32, r0 = blockIdx.y * 32;
  int tx = threadIdx.x, ty = threadIdx.y;  // block (32,8)
#pragma unroll
  for (int i = 0; i < 4; i++)
    tile[ty + i * 8][tx] = W[(size_t)(r0 + ty + i * 8) * C + c0 + tx];
  __syncthreads();
#pragma unroll
  for (int i = 0; i < 4; i++) {
    float v = tile[tx][ty + i * 8];
    size_t o = (size_t)(c0 + ty + i * 8) * R + r0 + tx;
    u16 h = f2bf(v);
    thi[o] = h;
    if (tlo) tlo[o] = f2bf(v - bf2f(h));
  }
}

// ---- GEMM1: Q,K = x @ {Wq,Wk} + bias, split output. 1-D grid nmt*16 ------
__launch_bounds__(256)
__global__ void k_gemm_qk(const u16* __restrict__ xhi, const u16* __restrict__ xlo,
                          const u16* __restrict__ wqThi, const u16* __restrict__ wqTlo,
                          const u16* __restrict__ wkThi, const u16* __restrict__ wkTlo,
                          const float* __restrict__ bq, const float* __restrict__ bk,
                          u16* __restrict__ qhi, u16* __restrict__ qlo,
                          u16* __restrict__ khi, u16* __restrict__ klo) {
  __shared__ __attribute__((aligned(16))) u16 lds[4][128][32];
  int wg = swz_wg();
  int nt = wg & 15, mt = wg >> 4;
  bool isK = (nt >= 8);
  const u16* bThi = isK ? wkThi : wqThi;
  const u16* bTlo = isK ? wkTlo : wqTlo;
  const float* bias = isK ? bk : bq;
  u16* ohi = isK ? khi : qhi;
  u16* olo = isK ? klo : qlo;
  int n0 = (nt & 7) * 128, m0 = mt * 128;

  int t = threadIdx.x, lane = t & 63, w = t >> 6;
  int wr = w >> 1, wc = w & 1, r16 = lane & 15, g = lane >> 4;

  f32x4 acc[4][4] = {};

  for (int k0 = 0; k0 < DD; k0 += 32) {
    stage_tile(xhi + (size_t)m0 * DD + k0, &lds[0][0][0], t, DD);
    stage_tile(xlo + (size_t)m0 * DD + k0, &lds[1][0][0], t, DD);
    stage_tile(bThi + (size_t)n0 * DD + k0, &lds[2][0][0], t, DD);
    stage_tile(bTlo + (size_t)n0 * DD + k0, &lds[3][0][0], t, DD);
    __syncthreads();
    bf16x8 bh[4], bl[4];
#pragma unroll
    for (int fn = 0; fn < 4; fn++) {
      int col = wc * 64 + fn * 16 + r16;
      bh[fn] = *(const bf16x8*)&lds[2][col][g * 8];
      bl[fn] = *(const bf16x8*)&lds[3][col][g * 8];
    }
#pragma unroll
    for (int fm = 0; fm < 4; fm++) {
      int row = wr * 64 + fm * 16 + r16;
      bf16x8 ah = *(const bf16x8*)&lds[0][row][g * 8];
      bf16x8 al = *(const bf16x8*)&lds[1][row][g * 8];
#pragma unroll
      for (int fn = 0; fn < 4; fn++) {
        acc[fm][fn] = __builtin_amdgcn_mfma_f32_16x16x32_bf16(ah, bh[fn], acc[fm][fn], 0, 0, 0);
        acc[fm][fn] = __builtin_amdgcn_mfma_f32_16x16x32_bf16(ah, bl[fn], acc[fm][fn], 0, 0, 0);
        acc[fm][fn] = __builtin_amdgcn_mfma_f32_16x16x32_bf16(al, bh[fn], acc[fm][fn], 0, 0, 0);
      }
    }
    __syncthreads();
  }
#pragma unroll
  for (int fm = 0; fm < 4; fm++) {
#pragma unroll
    for (int fn = 0; fn < 4; fn++) {
      int col = n0 + wc * 64 + fn * 16 + r16;
      float bv = bias[col];
      int row = m0 + wr * 64 + fm * 16 + g * 4;
#pragma unroll
      for (int i = 0; i < 4; i++) {
        float v = acc[fm][fn][i] + bv;
        u16 h = f2bf(v);
        size_t o = (size_t)(row + i) * DD + col;
        ohi[o] = h;
        olo[o] = f2bf(v - bf2f(h));
      }
    }
  }
}

// ---- GEMM2: S[b] = Q[b] @ K[b]^T (fp32). 1-D grid nb*256 -----------------
__launch_bounds__(256)
__global__ void k_gemm_s(const u16* __restrict__ qhi, const u16* __restrict__ qlo,
                         const u16* __restrict__ khi, const u16* __restrict__ klo,
                         float* __restrict__ S) {
  __shared__ __attribute__((aligned(16))) u16 lds[4][128][32];
  int wg = swz_wg();
  int b = wg >> 8, mtS = wg & 15, ntS = (wg >> 4) & 15;
  const u16* qh = qhi + (size_t)b * NN * DD;
  const u16* ql = qlo + (size_t)b * NN * DD;
  const u16* kh = khi + (size_t)b * NN * DD;
  const u16* kl = klo + (size_t)b * NN * DD;
  float* Sb = S + (size_t)b * NN * NN;

  int t = threadIdx.x, lane = t & 63, w = t >> 6;
  int wr = w >> 1, wc = w & 1, r16 = lane & 15, g = lane >> 4;
  int a0 = ntS * 128, b0 = mtS * 128;

  f32x4 acc[4][4] = {};

  for (int k0 = 0; k0 < DD; k0 += 32) {
    stage_tile(qh + (size_t)a0 * DD + k0, &lds[0][0][0], t, DD);
    stage_tile(ql + (size_t)a0 * DD + k0, &lds[1][0][0], t, DD);
    stage_tile(kh + (size_t)b0 * DD + k0, &lds[2][0][0], t, DD);
    stage_tile(kl + (size_t)b0 * DD + k0, &lds[3][0][0], t, DD);
    __syncthreads();
    bf16x8 bh[4], bl[4];
#pragma unroll
    for (int fn = 0; fn < 4; fn++) {
      int col = wc * 64 + fn * 16 + r16;
      bh[fn] = *(const bf16x8*)&lds[2][col][g * 8];
      bl[fn] = *(const bf16x8*)&lds[3][col][g * 8];
    }
#pragma unroll
    for (int fm = 0; fm < 4; fm++) {
      int row = wr * 64 + fm * 16 + r16;
      bf16x8 ah = *(const bf16x8*)&lds[0][row][g * 8];
      bf16x8 al = *(const bf16x8*)&lds[1][row][g * 8];
#pragma unroll
      for (int fn = 0; fn < 4; fn++) {
        acc[fm][fn] = __builtin_amdgcn_mfma_f32_16x16x32_bf16(ah, bh[fn], acc[fm][fn], 0, 0, 0);
        acc[fm][fn] = __builtin_amdgcn_mfma_f32_16x16x32_bf16(ah, bl[fn], acc[fm][fn], 0, 0, 0);
        acc[fm][fn] = __builtin_amdgcn_mfma_f32_16x16x32_bf16(al, bh[fn], acc[fm][fn], 0, 0, 0);
      }
    }
    __syncthreads();
  }
#pragma unroll
  for (int fm = 0; fm < 4; fm++) {
#pragma unroll
    for (int fn = 0; fn < 4; fn++) {
      int col = b0 + wc * 64 + fn * 16 + r16;
      int row = a0 + wr * 64 + fm * 16 + g * 4;
#pragma unroll
      for (int i = 0; i < 4; i++)
        Sb[(size_t)(row + i) * NN + col] = acc[fm][fn][i];
    }
  }
}

// ---- softmax rows of S -> P bf16 IN PLACE (P row r = first 4KB of S row r)
__global__ void k_softmax(float* __restrict__ S, int nrows) {
  int w = threadIdx.x >> 6, lane = threadIdx.x & 63;
  int row = blockIdx.x * 4 + w;
  if (row >= nrows) return;
  const float4* Sr = (const float4*)(S + (size_t)row * NN);
  float4 v[8];
  float mx = -3.4e38f;
#pragma unroll
  for (int j = 0; j < 8; j++) {
    v[j] = Sr[j * 64 + lane];
    mx = fmaxf(mx, fmaxf(fmaxf(v[j].x, v[j].y), fmaxf(v[j].z, v[j].w)));
  }
#pragma unroll
  for (int o = 32; o > 0; o >>= 1) mx = fmaxf(mx, __shfl_xor(mx, o));
  float e[32];
  float sum = 0.f;
#pragma unroll
  for (int j = 0; j < 8; j++) {
    e[j * 4 + 0] = __expf(v[j].x - mx);
    e[j * 4 + 1] = __expf(v[j].y - mx);
    e[j * 4 + 2] = __expf(v[j].z - mx);
    e[j * 4 + 3] = __expf(v[j].w - mx);
    sum += e[j * 4 + 0] + e[j * 4 + 1] + e[j * 4 + 2] + e[j * 4 + 3];
  }
#pragma unroll
  for (int o = 32; o > 0; o >>= 1) sum += __shfl_xor(sum, o);
  float inv = 1.0f / sum;  // depends on every lane's loads -> safe to overwrite row
  ushort4* Pr = (ushort4*)((u16*)S + (size_t)row * PSTRIDE);
#pragma unroll
  for (int j = 0; j < 8; j++) {
    ushort4 pv;
    pv.x = f2bf(e[j * 4 + 0] * inv);
    pv.y = f2bf(e[j * 4 + 1] * inv);
    pv.z = f2bf(e[j * 4 + 2] * inv);
    pv.w = f2bf(e[j * 4 + 3] * inv);
    Pr[j * 64 + lane] = pv;
  }
}

// ---- GEMM3: out[b] = P[b] @ Wout + bout (plain bf16). 1-D grid nb*128 ----
__launch_bounds__(256)
__global__ void k_gemm_out(const u16* __restrict__ P, const u16* __restrict__ woutT,
                           const float* __restrict__ bout, float* __restrict__ out) {
  __shared__ __attribute__((aligned(16))) u16 lds[2][128][32];
  int wg = swz_wg();
  int b = wg >> 7, dt = wg & 7, ntt = (wg >> 3) & 15;
  const u16* Pb = P + (size_t)b * NN * PSTRIDE;
  float* ob = out + (size_t)b * NN * DD;

  int t = threadIdx.x, lane = t & 63, w = t >> 6;
  int wr = w >> 1, wc = w & 1, r16 = lane & 15, g = lane >> 4;

  f32x4 acc[4][4] = {};

  for (int k0 = 0; k0 < NN; k0 += 32) {
    stage_tile(Pb + (size_t)(ntt * 128) * PSTRIDE + k0, &lds[0][0][0], t, PSTRIDE);
    stage_tile(woutT + (size_t)(dt * 128) * NN + k0, &lds[1][0][0], t, NN);
    __syncthreads();
    bf16x8 bh[4];
#pragma unroll
    for (int fn = 0; fn < 4; fn++)
      bh[fn] = *(const bf16x8*)&lds[1][wc * 64 + fn * 16 + r16][g * 8];
#pragma unroll
    for (int fm = 0; fm < 4; fm++) {
      bf16x8 ah = *(const bf16x8*)&lds[0][wr * 64 + fm * 16 + r16][g * 8];
#pragma unroll
      for (int fn = 0; fn < 4; fn++)
        acc[fm][fn] = __builtin_amdgcn_mfma_f32_16x16x32_bf16(ah, bh[fn], acc[fm][fn], 0, 0, 0);
    }
    __syncthreads();
  }
#pragma unroll
  for (int fm = 0; fm < 4; fm++) {
#pragma unroll
    for (int fn = 0; fn < 4; fn++) {
      int col = dt * 128 + wc * 64 + fn * 16 + r16;
      float bv = bout[col];
      int row = ntt * 128 + wr * 64 + fm * 16 + g * 4;
#pragma unroll
      for (int i = 0; i < 4; i++)
        ob[(size_t)(row + i) * DD + col] = acc[fm][fn][i] + bv;
    }
  }
}

extern "C" void kernel_launch(void* const* d_in, const int* in_sizes, int n_in,
                              void* d_out, int out_size, void* d_ws, size_t ws_size,
                              hipStream_t stream) {
  const float* x = (const float*)d_in[0];
  const float* Wq = (const float*)d_in[1];
  const float* bq = (const float*)d_in[2];
  const float* Wk = (const float*)d_in[3];
  const float* bk = (const float*)d_in[4];
  const float* Wout = (const float*)d_in[5];
  const float* bout = (const float*)d_in[6];
  float* out = (float*)d_out;
  char* ws = (char*)d_ws;

  const size_t MB = 1ull << 20;
  u16* wqThi = (u16*)(ws + 0 * MB);
  u16* wqTlo = (u16*)(ws + 2 * MB);
  u16* wkThi = (u16*)(ws + 4 * MB);
  u16* wkTlo = (u16*)(ws + 6 * MB);
  u16* woutT = (u16*)(ws + 8 * MB);  // 4 MiB [1024][2048]
  char* base = ws + 12 * MB;

  dim3 tb(32, 8, 1);
  k_transpose_split<<<dim3(32, 32, 1), tb, 0, stream>>>(Wq, wqThi, wqTlo, 1024, 1024);
  k_transpose_split<<<dim3(32, 32, 1), tb, 0, stream>>>(Wk, wkThi, wkTlo, 1024, 1024);
  k_transpose_split<<<dim3(32, 64, 1), tb, 0, stream>>>(Wout, woutT, (u16*)nullptr, 2048, 1024);

  if (ws_size >= 204 * MB) {
    // Tier A: QK planes all batches (128MB) + R 64MB (xplanes, then S halves)
    u16* qhi = (u16*)(base);
    u16* qlo = (u16*)(base + 32 * MB);
    u16* khi = (u16*)(base + 64 * MB);
    u16* klo = (u16*)(base + 96 * MB);
    char* R = base + 128 * MB;
    u16* xhi = (u16*)R;
    u16* xlo = (u16*)(R + 32 * MB);
    float* S = (float*)R;

    k_split<<<2048, 256, 0, stream>>>(x, xhi, xlo, (long)MT * DD / 4);
    k_gemm_qk<<<128 * 16, 256, 0, stream>>>(xhi, xlo, wqThi, wqTlo, wkThi, wkTlo,
                                            bq, bk, qhi, qlo, khi, klo);
    for (int h = 0; h < 2; h++) {
      size_t qo = (size_t)h * 4 * NN * DD;
      k_gemm_s<<<4 * 256, 256, 0, stream>>>(qhi + qo, qlo + qo, khi + qo, klo + qo, S);
      k_softmax<<<4 * NN / 4, 256, 0, stream>>>(S, 4 * NN);
      k_gemm_out<<<4 * 128, 256, 0, stream>>>((const u16*)S, woutT, bout,
                                              out + (size_t)h * 4 * NN * DD);
    }
  } else if (ws_size >= 156 * MB) {
    // Tier B: QK planes all batches + R 16MB
    u16* qhi = (u16*)(base);
    u16* qlo = (u16*)(base + 32 * MB);
    u16* khi = (u16*)(base + 64 * MB);
    u16* klo = (u16*)(base + 96 * MB);
    char* R = base + 128 * MB;
    u16* xhi = (u16*)R;
    u16* xlo = (u16*)(R + 8 * MB);
    float* S = (float*)R;
    for (int c = 0; c < 4; c++) {  // chunks of 2 batches for QK
      size_t xo = (size_t)c * 2 * NN * DD;
      k_split<<<1024, 256, 0, stream>>>(x + xo, xhi, xlo, (long)2 * NN * DD / 4);
      k_gemm_qk<<<32 * 16, 256, 0, stream>>>(xhi, xlo, wqThi, wqTlo, wkThi, wkTlo,
                                             bq, bk, qhi + xo, qlo + xo, khi + xo, klo + xo);
    }
    for (int b = 0; b < BB; b++) {
      size_t qo = (size_t)b * NN * DD;
      k_gemm_s<<<256, 256, 0, stream>>>(qhi + qo, qlo + qo, khi + qo, klo + qo, S);
      k_softmax<<<NN / 4, 256, 0, stream>>>(S, NN);
      k_gemm_out<<<128, 256, 0, stream>>>((const u16*)S, woutT, bout, out + qo);
    }
  } else {
    // Tier C: fully per-batch (44MB)
    u16* qhi = (u16*)(base);
    u16* qlo = (u16*)(base + 4 * MB);
    u16* khi = (u16*)(base + 8 * MB);
    u16* klo = (u16*)(base + 12 * MB);
    char* R = base + 16 * MB;
    u16* xhi = (u16*)R;
    u16* xlo = (u16*)(R + 4 * MB);
    float* S = (float*)R;
    for (int b = 0; b < BB; b++) {
      size_t qo = (size_t)b * NN * DD;
      k_split<<<512, 256, 0, stream>>>(x + qo, xhi, xlo, (long)NN * DD / 4);
      k_gemm_qk<<<16 * 16, 256, 0, stream>>>(xhi, xlo, wqThi, wqTlo, wkThi, wkTlo,
                                             bq, bk, qhi, qlo, khi, klo);
      k_gemm_s<<<256, 256, 0, stream>>>(qhi, qlo, khi, klo, S);
      k_softmax<<<NN / 4, 256, 0, stream>>>(S, NN);
      k_gemm_out<<<128, 256, 0, stream>>>((const u16*)S, woutT, bout, out + qo);
    }
  }
}

// Round 3
// 575.532 us; speedup vs baseline: 2.1291x; 1.0509x over previous
//
#include <hip/hip_runtime.h>

// SelfAttention: out = softmax((xWq+bq)(xWk+bk)^T) @ Wout + bout
// B=8, N=2048, D=1024, fp32 in/out.
// Round 3: algebraic reduction S = x (WqWk^T) x^T.
//   Mt = Wk@Wq^T (split GEMM, 1024^2), y = x@Mt^T (split GEMM),
//   S = y@x^T (split GEMM, fp32 out), softmax(+c2 bias col term), P@Wout.
// Bias terms: S += (xWqbk)[n] (row-const, cancels in softmax) + (x Wk bq)[m]
//   (kept: c2) + bq.bk (cancels). c2 added in softmax kernel.
// All score-chain GEMMs use bf16 hi/lo split inputs with 3 MFMAs per product.

typedef unsigned short u16;
typedef __bf16 bf16x8 __attribute__((ext_vector_type(8)));
typedef float f32x4 __attribute__((ext_vector_type(4)));

#define BB 8
#define NN 2048
#define DD 1024
#define MT (BB * NN)
#define PSTRIDE 4096  // u16 elems per P row (in-place over fp32 S rows)

static __device__ __forceinline__ u16 f2bf(float f) {
  unsigned u = __builtin_bit_cast(unsigned, f);
  u += 0x7FFFu + ((u >> 16) & 1u);
  return (u16)(u >> 16);
}
static __device__ __forceinline__ float bf2f(u16 h) {
  unsigned u = ((unsigned)h) << 16;
  return __builtin_bit_cast(float, u);
}

static __device__ __forceinline__ void gload16(const void* g, void* l) {
  __builtin_amdgcn_global_load_lds((const __attribute__((address_space(1))) void*)g,
                                   (__attribute__((address_space(3))) void*)l, 16, 0, 0);
}

// stage a [128][32]-u16 linear tile from gsrc (tile origin), row stride ldg elems
static __device__ __forceinline__ void stage_tile(const u16* __restrict__ gsrc,
                                                  u16* plane, int t, int ldg) {
  int w = t >> 6;
#pragma unroll
  for (int j = 0; j < 2; j++) {
    int idx = t + j * 256;  // 8-elem chunk index 0..511
    const u16* g = gsrc + (size_t)(idx >> 2) * ldg + (idx & 3) * 8;
    u16* lp = plane + (w * 64 + j * 256) * 8;  // wave-uniform base; HW adds lane*16B
    gload16(g, lp);
  }
}

// bijective XCD swizzle over a 1-D grid (gridDim.x % 8 == 0 for all callers)
static __device__ __forceinline__ int swz_wg() {
  int nwg = gridDim.x;
  int orig = blockIdx.x;
  int q = nwg >> 3;
  return (orig & 7) * q + (orig >> 3);
}

// ---- prep: split fp32 -> hi/lo bf16 planes -------------------------------
__global__ void k_split(const float* __restrict__ x, u16* __restrict__ hi,
                        u16* __restrict__ lo, long n4) {
  long i = (long)blockIdx.x * blockDim.x + threadIdx.x;
  long stride = (long)gridDim.x * blockDim.x;
  for (; i < n4; i += stride) {
    float4 v = ((const float4*)x)[i];
    u16 h0 = f2bf(v.x), h1 = f2bf(v.y), h2 = f2bf(v.z), h3 = f2bf(v.w);
    ushort4 hv; hv.x = h0; hv.y = h1; hv.z = h2; hv.w = h3;
    ushort4 lv;
    lv.x = f2bf(v.x - bf2f(h0)); lv.y = f2bf(v.y - bf2f(h1));
    lv.z = f2bf(v.z - bf2f(h2)); lv.w = f2bf(v.w - bf2f(h3));
    ((ushort4*)hi)[i] = hv;
    ((ushort4*)lo)[i] = lv;
  }
}

// ---- prep: transpose RxC fp32 -> CxR bf16 (hi only) ----------------------
__global__ void k_transpose_split(const float* __restrict__ W, u16* __restrict__ thi,
                                  int R, int C) {
  __shared__ float tile[32][33];
  int c0 = blockIdx.x * 32, r0 = blockIdx.y * 32;
  int tx = threadIdx.x, ty = threadIdx.y;  // block (32,8)
#pragma unroll
  for (int i = 0; i < 4; i++)
    tile[ty + i * 8][tx] = W[(size_t)(r0 + ty + i * 8) * C + c0 + tx];
  __syncthreads();
#pragma unroll
  for (int i = 0; i < 4; i++) {
    float v = tile[tx][ty + i * 8];
    thi[(size_t)(c0 + ty + i * 8) * R + r0 + tx] = f2bf(v);
  }
}

// ---- matvec: out[r] = A[r,:] . v  (wave per row) -------------------------
__global__ void k_matvec(const float* __restrict__ A, const float* __restrict__ v,
                         float* __restrict__ out, int cols) {
  int w = threadIdx.x >> 6, lane = threadIdx.x & 63;
  int row = blockIdx.x * 4 + w;
  const float4* Ar = (const float4*)(A + (size_t)row * cols);
  const float4* vv = (const float4*)v;
  float s = 0.f;
  for (int j = lane; j < cols / 4; j += 64) {
    float4 a = Ar[j], b = vv[j];
    s += a.x * b.x + a.y * b.y + a.z * b.z + a.w * b.w;
  }
#pragma unroll
  for (int o = 32; o > 0; o >>= 1) s += __shfl_xor(s, o);
  if (lane == 0) out[row] = s;
}

// ---- split GEMM: C = A @ B^T, split bf16 planes in, split planes out -----
// A rows indexed by output row (ld KD), B rows by output col (ld KD).
// grid 1-D = (MA/128)*(NB/128); nnt = NB/128.
__launch_bounds__(256)
__global__ void k_gemm_split(const u16* __restrict__ ah_g, const u16* __restrict__ al_g,
                             const u16* __restrict__ bh_g, const u16* __restrict__ bl_g,
                             u16* __restrict__ ohi, u16* __restrict__ olo,
                             int KD, int nnt, int ldo) {
  __shared__ __attribute__((aligned(16))) u16 lds[4][128][32];
  int wg = swz_wg();
  int nt = wg % nnt, mt = wg / nnt;
  int n0 = nt * 128, m0 = mt * 128;

  int t = threadIdx.x, lane = t & 63, w = t >> 6;
  int wr = w >> 1, wc = w & 1, r16 = lane & 15, g = lane >> 4;

  f32x4 acc[4][4] = {};

  for (int k0 = 0; k0 < KD; k0 += 32) {
    stage_tile(ah_g + (size_t)m0 * KD + k0, &lds[0][0][0], t, KD);
    stage_tile(al_g + (size_t)m0 * KD + k0, &lds[1][0][0], t, KD);
    stage_tile(bh_g + (size_t)n0 * KD + k0, &lds[2][0][0], t, KD);
    stage_tile(bl_g + (size_t)n0 * KD + k0, &lds[3][0][0], t, KD);
    __syncthreads();
    bf16x8 bh[4], bl[4];
#pragma unroll
    for (int fn = 0; fn < 4; fn++) {
      int col = wc * 64 + fn * 16 + r16;
      bh[fn] = *(const bf16x8*)&lds[2][col][g * 8];
      bl[fn] = *(const bf16x8*)&lds[3][col][g * 8];
    }
#pragma unroll
    for (int fm = 0; fm < 4; fm++) {
      int row = wr * 64 + fm * 16 + r16;
      bf16x8 ah = *(const bf16x8*)&lds[0][row][g * 8];
      bf16x8 al = *(const bf16x8*)&lds[1][row][g * 8];
#pragma unroll
      for (int fn = 0; fn < 4; fn++) {
        acc[fm][fn] = __builtin_amdgcn_mfma_f32_16x16x32_bf16(ah, bh[fn], acc[fm][fn], 0, 0, 0);
        acc[fm][fn] = __builtin_amdgcn_mfma_f32_16x16x32_bf16(ah, bl[fn], acc[fm][fn], 0, 0, 0);
        acc[fm][fn] = __builtin_amdgcn_mfma_f32_16x16x32_bf16(al, bh[fn], acc[fm][fn], 0, 0, 0);
      }
    }
    __syncthreads();
  }
#pragma unroll
  for (int fm = 0; fm < 4; fm++) {
#pragma unroll
    for (int fn = 0; fn < 4; fn++) {
      int col = n0 + wc * 64 + fn * 16 + r16;
      int row = m0 + wr * 64 + fm * 16 + g * 4;
#pragma unroll
      for (int i = 0; i < 4; i++) {
        float v = acc[fm][fn][i];
        u16 h = f2bf(v);
        size_t o = (size_t)(row + i) * ldo + col;
        ohi[o] = h;
        olo[o] = f2bf(v - bf2f(h));
      }
    }
  }
}

// ---- S[b] = y[b] @ x[b]^T (fp32 out). 1-D grid nb*256 --------------------
__launch_bounds__(256)
__global__ void k_gemm_s(const u16* __restrict__ yhi, const u16* __restrict__ ylo,
                         const u16* __restrict__ xhi, const u16* __restrict__ xlo,
                         float* __restrict__ S) {
  __shared__ __attribute__((aligned(16))) u16 lds[4][128][32];
  int wg = swz_wg();
  int b = wg >> 8, mtS = wg & 15, ntS = (wg >> 4) & 15;
  const u16* yh = yhi + (size_t)b * NN * DD;
  const u16* yl = ylo + (size_t)b * NN * DD;
  const u16* xh = xhi + (size_t)b * NN * DD;
  const u16* xl = xlo + (size_t)b * NN * DD;
  float* Sb = S + (size_t)b * NN * NN;

  int t = threadIdx.x, lane = t & 63, w = t >> 6;
  int wr = w >> 1, wc = w & 1, r16 = lane & 15, g = lane >> 4;
  int a0 = ntS * 128, b0 = mtS * 128;

  f32x4 acc[4][4] = {};

  for (int k0 = 0; k0 < DD; k0 += 32) {
    stage_tile(yh + (size_t)a0 * DD + k0, &lds[0][0][0], t, DD);
    stage_tile(yl + (size_t)a0 * DD + k0, &lds[1][0][0], t, DD);
    stage_tile(xh + (size_t)b0 * DD + k0, &lds[2][0][0], t, DD);
    stage_tile(xl + (size_t)b0 * DD + k0, &lds[3][0][0], t, DD);
    __syncthreads();
    bf16x8 bh[4], bl[4];
#pragma unroll
    for (int fn = 0; fn < 4; fn++) {
      int col = wc * 64 + fn * 16 + r16;
      bh[fn] = *(const bf16x8*)&lds[2][col][g * 8];
      bl[fn] = *(const bf16x8*)&lds[3][col][g * 8];
    }
#pragma unroll
    for (int fm = 0; fm < 4; fm++) {
      int row = wr * 64 + fm * 16 + r16;
      bf16x8 ah = *(const bf16x8*)&lds[0][row][g * 8];
      bf16x8 al = *(const bf16x8*)&lds[1][row][g * 8];
#pragma unroll
      for (int fn = 0; fn < 4; fn++) {
        acc[fm][fn] = __builtin_amdgcn_mfma_f32_16x16x32_bf16(ah, bh[fn], acc[fm][fn], 0, 0, 0);
        acc[fm][fn] = __builtin_amdgcn_mfma_f32_16x16x32_bf16(ah, bl[fn], acc[fm][fn], 0, 0, 0);
        acc[fm][fn] = __builtin_amdgcn_mfma_f32_16x16x32_bf16(al, bh[fn], acc[fm][fn], 0, 0, 0);
      }
    }
    __syncthreads();
  }
#pragma unroll
  for (int fm = 0; fm < 4; fm++) {
#pragma unroll
    for (int fn = 0; fn < 4; fn++) {
      int col = b0 + wc * 64 + fn * 16 + r16;
      int row = a0 + wr * 64 + fm * 16 + g * 4;
#pragma unroll
      for (int i = 0; i < 4; i++)
        Sb[(size_t)(row + i) * NN + col] = acc[fm][fn][i];
    }
  }
}

// ---- softmax rows of S (+ per-col bias c2) -> P bf16 IN PLACE ------------
__global__ void k_softmax(float* __restrict__ S, const float* __restrict__ c2, int nrows) {
  int w = threadIdx.x >> 6, lane = threadIdx.x & 63;
  int row = blockIdx.x * 4 + w;
  if (row >= nrows) return;
  const float4* Sr = (const float4*)(S + (size_t)row * NN);
  const float4* c2b = (const float4*)(c2 + ((size_t)(row >> 11) << 11));
  float4 v[8];
  float mx = -3.4e38f;
#pragma unroll
  for (int j = 0; j < 8; j++) {
    v[j] = Sr[j * 64 + lane];
    float4 c = c2b[j * 64 + lane];
    v[j].x += c.x; v[j].y += c.y; v[j].z += c.z; v[j].w += c.w;
    mx = fmaxf(mx, fmaxf(fmaxf(v[j].x, v[j].y), fmaxf(v[j].z, v[j].w)));
  }
#pragma unroll
  for (int o = 32; o > 0; o >>= 1) mx = fmaxf(mx, __shfl_xor(mx, o));
  float e[32];
  float sum = 0.f;
#pragma unroll
  for (int j = 0; j < 8; j++) {
    e[j * 4 + 0] = __expf(v[j].x - mx);
    e[j * 4 + 1] = __expf(v[j].y - mx);
    e[j * 4 + 2] = __expf(v[j].z - mx);
    e[j * 4 + 3] = __expf(v[j].w - mx);
    sum += e[j * 4 + 0] + e[j * 4 + 1] + e[j * 4 + 2] + e[j * 4 + 3];
  }
#pragma unroll
  for (int o = 32; o > 0; o >>= 1) sum += __shfl_xor(sum, o);
  float inv = 1.0f / sum;  // depends on every lane's loads -> safe to overwrite row
  ushort4* Pr = (ushort4*)((u16*)S + (size_t)row * PSTRIDE);
#pragma unroll
  for (int j = 0; j < 8; j++) {
    ushort4 pv;
    pv.x = f2bf(e[j * 4 + 0] * inv);
    pv.y = f2bf(e[j * 4 + 1] * inv);
    pv.z = f2bf(e[j * 4 + 2] * inv);
    pv.w = f2bf(e[j * 4 + 3] * inv);
    Pr[j * 64 + lane] = pv;
  }
}

// ---- out[b] = P[b] @ Wout + bout (plain bf16). 1-D grid nb*128 -----------
__launch_bounds__(256)
__global__ void k_gemm_out(const u16* __restrict__ P, const u16* __restrict__ woutT,
                           const float* __restrict__ bout, float* __restrict__ out) {
  __shared__ __attribute__((aligned(16))) u16 lds[2][128][32];
  int wg = swz_wg();
  int b = wg >> 7, dt = wg & 7, ntt = (wg >> 3) & 15;
  const u16* Pb = P + (size_t)b * NN * PSTRIDE;
  float* ob = out + (size_t)b * NN * DD;

  int t = threadIdx.x, lane = t & 63, w = t >> 6;
  int wr = w >> 1, wc = w & 1, r16 = lane & 15, g = lane >> 4;

  f32x4 acc[4][4] = {};

  for (int k0 = 0; k0 < NN; k0 += 32) {
    stage_tile(Pb + (size_t)(ntt * 128) * PSTRIDE + k0, &lds[0][0][0], t, PSTRIDE);
    stage_tile(woutT + (size_t)(dt * 128) * NN + k0, &lds[1][0][0], t, NN);
    __syncthreads();
    bf16x8 bh[4];
#pragma unroll
    for (int fn = 0; fn < 4; fn++)
      bh[fn] = *(const bf16x8*)&lds[1][wc * 64 + fn * 16 + r16][g * 8];
#pragma unroll
    for (int fm = 0; fm < 4; fm++) {
      bf16x8 ah = *(const bf16x8*)&lds[0][wr * 64 + fm * 16 + r16][g * 8];
#pragma unroll
      for (int fn = 0; fn < 4; fn++)
        acc[fm][fn] = __builtin_amdgcn_mfma_f32_16x16x32_bf16(ah, bh[fn], acc[fm][fn], 0, 0, 0);
    }
    __syncthreads();
  }
#pragma unroll
  for (int fm = 0; fm < 4; fm++) {
#pragma unroll
    for (int fn = 0; fn < 4; fn++) {
      int col = dt * 128 + wc * 64 + fn * 16 + r16;
      float bv = bout[col];
      int row = ntt * 128 + wr * 64 + fm * 16 + g * 4;
#pragma unroll
      for (int i = 0; i < 4; i++)
        ob[(size_t)(row + i) * DD + col] = acc[fm][fn][i] + bv;
    }
  }
}

extern "C" void kernel_launch(void* const* d_in, const int* in_sizes, int n_in,
                              void* d_out, int out_size, void* d_ws, size_t ws_size,
                              hipStream_t stream) {
  const float* x = (const float*)d_in[0];
  const float* Wq = (const float*)d_in[1];
  const float* bq = (const float*)d_in[2];
  const float* Wk = (const float*)d_in[3];
  const float* bk = (const float*)d_in[4];
  const float* Wout = (const float*)d_in[5];
  const float* bout = (const float*)d_in[6];
  float* out = (float*)d_out;
  char* ws = (char*)d_ws;

  const size_t MB = 1ull << 20;
  // prep region [0,12MB): Mt planes, woutT, v2, c2
  u16* mth = (u16*)(ws + 0 * MB);
  u16* mtl = (u16*)(ws + 2 * MB);
  u16* woutT = (u16*)(ws + 4 * MB);            // 4 MiB [1024][2048]
  float* v2 = (float*)(ws + 8 * MB);           // 4 KiB
  float* c2 = (float*)(ws + 8 * MB + 65536);   // 64 KiB
  char* base = ws + 12 * MB;

  dim3 tb(32, 8, 1);

  if (ws_size >= 204 * MB) {
    // Tier A: xh/xl [0,64), yh/yl [64,128), S/scratch [128,192)
    u16* xh = (u16*)(base);
    u16* xl = (u16*)(base + 32 * MB);
    u16* yh = (u16*)(base + 64 * MB);
    u16* yl = (u16*)(base + 96 * MB);
    char* R = base + 128 * MB;  // 64 MiB scratch: Wq/Wk planes, then S
    u16* wqh = (u16*)(R);
    u16* wql = (u16*)(R + 2 * MB);
    u16* wkh = (u16*)(R + 4 * MB);
    u16* wkl = (u16*)(R + 6 * MB);
    float* S = (float*)R;

    // prep
    k_split<<<256, 256, 0, stream>>>(Wq, wqh, wql, (long)DD * DD / 4);
    k_split<<<256, 256, 0, stream>>>(Wk, wkh, wkl, (long)DD * DD / 4);
    k_gemm_split<<<64, 256, 0, stream>>>(wkh, wkl, wqh, wql, mth, mtl, DD, 8, DD);
    k_transpose_split<<<dim3(32, 64, 1), tb, 0, stream>>>(Wout, woutT, 2048, 1024);
    k_matvec<<<256, 256, 0, stream>>>(Wk, bq, v2, DD);
    k_matvec<<<4096, 256, 0, stream>>>(x, v2, c2, DD);
    k_split<<<2048, 256, 0, stream>>>(x, xh, xl, (long)MT * DD / 4);
    // y = x @ Mt^T
    k_gemm_split<<<1024, 256, 0, stream>>>(xh, xl, mth, mtl, yh, yl, DD, 8, DD);
    // per 4-batch half: S, softmax, out
    for (int h = 0; h < 2; h++) {
      size_t qo = (size_t)h * 4 * NN * DD;
      k_gemm_s<<<4 * 256, 256, 0, stream>>>(yh + qo, yl + qo, xh + qo, xl + qo, S);
      k_softmax<<<4 * NN / 4, 256, 0, stream>>>(S, c2 + (size_t)h * 4 * NN, 4 * NN);
      k_gemm_out<<<4 * 128, 256, 0, stream>>>((const u16*)S, woutT, bout, out + qo);
    }
  } else if (ws_size >= 156 * MB) {
    // Tier B: xh/xl [0,64), yh/yl [64,128), S 16MB at [128,144)
    u16* xh = (u16*)(base);
    u16* xl = (u16*)(base + 32 * MB);
    u16* yh = (u16*)(base + 64 * MB);
    u16* yl = (u16*)(base + 96 * MB);
    char* R = base + 128 * MB;
    u16* wqh = (u16*)(R);
    u16* wql = (u16*)(R + 2 * MB);
    u16* wkh = (u16*)(R + 4 * MB);
    u16* wkl = (u16*)(R + 6 * MB);
    float* S = (float*)R;

    k_split<<<256, 256, 0, stream>>>(Wq, wqh, wql, (long)DD * DD / 4);
    k_split<<<256, 256, 0, stream>>>(Wk, wkh, wkl, (long)DD * DD / 4);
    k_gemm_split<<<64, 256, 0, stream>>>(wkh, wkl, wqh, wql, mth, mtl, DD, 8, DD);
    k_transpose_split<<<dim3(32, 64, 1), tb, 0, stream>>>(Wout, woutT, 2048, 1024);
    k_matvec<<<256, 256, 0, stream>>>(Wk, bq, v2, DD);
    k_matvec<<<4096, 256, 0, stream>>>(x, v2, c2, DD);
    k_split<<<2048, 256, 0, stream>>>(x, xh, xl, (long)MT * DD / 4);
    k_gemm_split<<<1024, 256, 0, stream>>>(xh, xl, mth, mtl, yh, yl, DD, 8, DD);
    for (int b = 0; b < BB; b++) {
      size_t qo = (size_t)b * NN * DD;
      k_gemm_s<<<256, 256, 0, stream>>>(yh + qo, yl + qo, xh + qo, xl + qo, S);
      k_softmax<<<NN / 4, 256, 0, stream>>>(S, c2 + (size_t)b * NN, NN);
      k_gemm_out<<<128, 256, 0, stream>>>((const u16*)S, woutT, bout, out + qo);
    }
  } else {
    // Tier C (60 MiB): per 2-batch chunk, xh/xl 16MB, yh/yl 16MB, S 16MB
    u16* xh = (u16*)(base);
    u16* xl = (u16*)(base + 8 * MB);
    u16* yh = (u16*)(base + 16 * MB);
    u16* yl = (u16*)(base + 24 * MB);
    char* R = base + 32 * MB;
    u16* wqh = (u16*)(R);
    u16* wql = (u16*)(R + 2 * MB);
    u16* wkh = (u16*)(R + 4 * MB);
    u16* wkl = (u16*)(R + 6 * MB);
    float* S = (float*)R;

    k_split<<<256, 256, 0, stream>>>(Wq, wqh, wql, (long)DD * DD / 4);
    k_split<<<256, 256, 0, stream>>>(Wk, wkh, wkl, (long)DD * DD / 4);
    k_gemm_split<<<64, 256, 0, stream>>>(wkh, wkl, wqh, wql, mth, mtl, DD, 8, DD);
    k_transpose_split<<<dim3(32, 64, 1), tb, 0, stream>>>(Wout, woutT, 2048, 1024);
    k_matvec<<<256, 256, 0, stream>>>(Wk, bq, v2, DD);
    k_matvec<<<4096, 256, 0, stream>>>(x, v2, c2, DD);
    for (int c = 0; c < 4; c++) {
      size_t xo = (size_t)c * 2 * NN * DD;
      k_split<<<1024, 256, 0, stream>>>(x + xo, xh, xl, (long)2 * NN * DD / 4);
      k_gemm_split<<<256, 256, 0, stream>>>(xh, xl, mth, mtl, yh, yl, DD, 8, DD);
      for (int bi = 0; bi < 2; bi++) {
        size_t lo = (size_t)bi * NN * DD;
        k_gemm_s<<<256, 256, 0, stream>>>(yh + lo, yl + lo, xh + lo, xl + lo, S);
        k_softmax<<<NN / 4, 256, 0, stream>>>(S, c2 + (size_t)(c * 2 + bi) * NN, NN);
        k_gemm_out<<<128, 256, 0, stream>>>((const u16*)S, woutT, bout, out + xo + lo);
      }
    }
  }
}